// Round 7
// baseline (1984.980 us; speedup 1.0000x reference)
//
#include <hip/hip_runtime.h>
#include <hip/hip_cooperative_groups.h>
#include <float.h>
#include <math.h>

namespace cg = cooperative_groups;

// Problem constants
#define BB 256
#define DD 512
#define NN 50000
#define KK 32
#define NS_ITERS 11
#define PARTS 8
#define PCH 6250

// Workspace layout (float offsets)
#define OFF_G     0         // UUT(65536) + TcTc(65536) + w(256) + m(50000); NS Pm reuses +0
#define OFF_SC    262144    // 64 scalars: 0=sumTc2 1=trCX 2=S_total 3=knn 4=wreg 5=s_ns
#define OFF_CS    262208    // 512 colsum X
#define OFF_CSS   262720    // 512 colsumsq X
#define ZERO_F    263232    // floats to memset
#define OFF_T     263232    // 256*512
#define OFF_TC    394304    // 256*512 Tc; later NS Y/Z
#define OFF_P     525376    // 256*512: top-k cand buffers; later NS Y2/Z2
#define OFF_H     656448    // 256*256
#define OFF_MUT   722496    // 512
#define OFF_XSQ   723008    // 50000
#define OFF_RUNI  781200    // 256*32 (int)
#define OFF_PW    789392    // 256*32 post_w
#define OFF_PRW   797584    // 256*32 pre_w normalized
#define OFF_D2    805776    // V = T@X^T (256*50000); later Kg/Mg

#define OFF_UUT   (OFF_G)
#define OFF_TCTC  (OFF_G + 65536)
#define OFF_W     (OFF_G + 131072)
#define OFF_M     (OFF_G + 131328)
#define OFF_KG    (OFF_D2)            // 256*4096
#define OFF_MG    (OFF_D2 + 1048576)  // 256*4096

typedef __attribute__((ext_vector_type(8))) short bf16x8;
typedef __attribute__((ext_vector_type(4))) float f32x4;

__device__ __forceinline__ float waveSum(float v) {
#pragma unroll
  for (int off = 32; off > 0; off >>= 1) v += __shfl_xor(v, off);
  return v;
}

// split fp32x4 -> bf16 hi/lo, write packed pairs to LDS
__device__ __forceinline__ void cvt_write(float4 v, unsigned short* hi, unsigned short* lo, int sa) {
  unsigned int b0 = __float_as_uint(v.x), b1 = __float_as_uint(v.y);
  unsigned int b2 = __float_as_uint(v.z), b3 = __float_as_uint(v.w);
  unsigned int h0 = b0 & 0xffff0000u, h1 = b1 & 0xffff0000u;
  unsigned int h2 = b2 & 0xffff0000u, h3 = b3 & 0xffff0000u;
  float l0 = v.x - __uint_as_float(h0), l1 = v.y - __uint_as_float(h1);
  float l2 = v.z - __uint_as_float(h2), l3 = v.w - __uint_as_float(h3);
  *(unsigned int*)&hi[sa]     = (h0 >> 16) | h1;
  *(unsigned int*)&hi[sa + 2] = (h2 >> 16) | h3;
  *(unsigned int*)&lo[sa]     = (__float_as_uint(l0) >> 16) | (__float_as_uint(l1) & 0xffff0000u);
  *(unsigned int*)&lo[sa + 2] = (__float_as_uint(l2) >> 16) | (__float_as_uint(l3) & 0xffff0000u);
}

// ---------------- generic 64x64-tile GEMM, C = scale * A @ B (nn) ----------------
__global__ void __launch_bounds__(256) k_g64_nn(const float* __restrict__ A,
                                                const float* __restrict__ B,
                                                float* __restrict__ C,
                                                int K, int lda, int ldb, int ldc, float scale) {
  __shared__ float As[64][65], Bs[64][65];
  int m0 = blockIdx.y * 64, n0 = blockIdx.x * 64;
  int t = threadIdx.x, tr = t >> 4, tc = t & 15;
  float acc[4][4] = {{0.f}};
  for (int k0 = 0; k0 < K; k0 += 64) {
#pragma unroll
    for (int p = 0; p < 16; ++p) {
      int l = t + 256 * p;
      int r = l >> 6, c = l & 63;
      As[r][c] = A[(m0 + r) * lda + k0 + c];
      Bs[r][c] = B[(k0 + r) * ldb + n0 + c];
    }
    __syncthreads();
#pragma unroll 16
    for (int kk = 0; kk < 64; ++kk) {
      float a[4], b[4];
#pragma unroll
      for (int u = 0; u < 4; ++u) a[u] = As[tr + 16 * u][kk];
#pragma unroll
      for (int v = 0; v < 4; ++v) b[v] = Bs[kk][tc + 16 * v];
#pragma unroll
      for (int u = 0; u < 4; ++u)
#pragma unroll
        for (int v = 0; v < 4; ++v) acc[u][v] += a[u] * b[v];
    }
    __syncthreads();
  }
#pragma unroll
  for (int u = 0; u < 4; ++u)
#pragma unroll
    for (int v = 0; v < 4; ++v)
      C[(m0 + tr + 16 * u) * ldc + n0 + tc + 16 * v] = acc[u][v] * scale;
}

// ---------------- generic 64x64-tile GEMM, C = scale * A @ B^T (nt) ----------------
__global__ void __launch_bounds__(256) k_g64_nt(const float* __restrict__ A,
                                                const float* __restrict__ B,
                                                float* __restrict__ C,
                                                int K, int lda, int ldb, int ldc, float scale) {
  __shared__ float As[64][65], Bs[64][65];
  int m0 = blockIdx.y * 64, n0 = blockIdx.x * 64;
  int t = threadIdx.x, tr = t >> 4, tc = t & 15;
  float acc[4][4] = {{0.f}};
  for (int k0 = 0; k0 < K; k0 += 64) {
#pragma unroll
    for (int p = 0; p < 16; ++p) {
      int l = t + 256 * p;
      int r = l >> 6, c = l & 63;
      As[r][c] = A[(m0 + r) * lda + k0 + c];
      Bs[r][c] = B[(n0 + r) * ldb + k0 + c];
    }
    __syncthreads();
#pragma unroll 16
    for (int kk = 0; kk < 64; ++kk) {
      float a[4], b[4];
#pragma unroll
      for (int u = 0; u < 4; ++u) a[u] = As[tr + 16 * u][kk];
#pragma unroll
      for (int v = 0; v < 4; ++v) b[v] = Bs[tc + 16 * v][kk];
#pragma unroll
      for (int u = 0; u < 4; ++u)
#pragma unroll
        for (int v = 0; v < 4; ++v) acc[u][v] += a[u] * b[v];
    }
    __syncthreads();
  }
#pragma unroll
  for (int u = 0; u < 4; ++u)
#pragma unroll
    for (int v = 0; v < 4; ++v)
      C[(m0 + tr + 16 * u) * ldc + n0 + tc + 16 * v] = acc[u][v] * scale;
}

// ---------------- V = T @ X^T  (MFMA bf16-split) ----------------
__global__ void __launch_bounds__(256) k_vgemm(const float* __restrict__ T,
                                               const float* __restrict__ X,
                                               float* __restrict__ V) {
  __shared__ unsigned short Ah[128 * 72], Al[128 * 72], Bh[128 * 72], Bl[128 * 72];
  int bj = blockIdx.x, bi = blockIdx.y;
  int t = threadIdx.x;
  int wave = t >> 6, lane = t & 63;
  int m0 = (wave >> 1) * 64, n0 = (wave & 1) * 64;
  int lrow = lane & 15, lq = lane >> 4;
  f32x4 acc[4][4] = {};
  for (int kc = 0; kc < 512; kc += 64) {
#pragma unroll
    for (int f = 0; f < 8; ++f) {
      int lin = f * 256 + t;
      int r = lin >> 4, c4 = lin & 15;
      int sa = r * 72 + c4 * 4;
      float4 va = *(const float4*)&T[(bi * 128 + r) * 512 + kc + c4 * 4];
      cvt_write(va, Ah, Al, sa);
      int jg = bj * 128 + r;
      float4 vb = {0.f, 0.f, 0.f, 0.f};
      if (jg < NN) vb = *(const float4*)&X[(size_t)jg * 512 + kc + c4 * 4];
      cvt_write(vb, Bh, Bl, sa);
    }
    __syncthreads();
#pragma unroll
    for (int ks = 0; ks < 2; ++ks) {
      int kb = ks * 32 + lq * 8;
      bf16x8 ah[4], al[4], bh[4], bl[4];
#pragma unroll
      for (int mi = 0; mi < 4; ++mi) {
        int ro = (m0 + mi * 16 + lrow) * 72 + kb;
        ah[mi] = *(const bf16x8*)&Ah[ro];
        al[mi] = *(const bf16x8*)&Al[ro];
      }
#pragma unroll
      for (int nj = 0; nj < 4; ++nj) {
        int ro = (n0 + nj * 16 + lrow) * 72 + kb;
        bh[nj] = *(const bf16x8*)&Bh[ro];
        bl[nj] = *(const bf16x8*)&Bl[ro];
      }
#pragma unroll
      for (int mi = 0; mi < 4; ++mi)
#pragma unroll
        for (int nj = 0; nj < 4; ++nj) {
          acc[mi][nj] = __builtin_amdgcn_mfma_f32_16x16x32_bf16(ah[mi], bh[nj], acc[mi][nj], 0, 0, 0);
          acc[mi][nj] = __builtin_amdgcn_mfma_f32_16x16x32_bf16(ah[mi], bl[nj], acc[mi][nj], 0, 0, 0);
          acc[mi][nj] = __builtin_amdgcn_mfma_f32_16x16x32_bf16(al[mi], bh[nj], acc[mi][nj], 0, 0, 0);
        }
    }
    __syncthreads();
  }
#pragma unroll
  for (int mi = 0; mi < 4; ++mi)
#pragma unroll
    for (int nj = 0; nj < 4; ++nj)
#pragma unroll
      for (int r = 0; r < 4; ++r) {
        int row = bi * 128 + m0 + mi * 16 + lq * 4 + r;
        int col = bj * 128 + n0 + nj * 16 + lrow;
        if (col < NN) V[(size_t)row * NN + col] = acc[mi][nj][r];
      }
}

// ---------------- UUT += U @ U^T, U = V - m (MFMA bf16-split, split-K atomic) ----------------
__global__ void __launch_bounds__(256) k_uut(const float* __restrict__ V,
                                             const float* __restrict__ m,
                                             float* __restrict__ UUT) {
  __shared__ unsigned short Ah[128 * 72], Al[128 * 72], Bh[128 * 72], Bl[128 * 72];
  const int pi_[3] = {0, 0, 1}, pj_[3] = {0, 1, 1};
  int bi = pi_[blockIdx.x], bj = pj_[blockIdx.x];
  int j0 = blockIdx.y * 1000, jlim = j0 + 1000;
  int t = threadIdx.x;
  int wave = t >> 6, lane = t & 63;
  int m0 = (wave >> 1) * 64, n0 = (wave & 1) * 64;
  int lrow = lane & 15, lq = lane >> 4;
  f32x4 acc[4][4] = {};
  for (int ch = 0; ch < 16; ++ch) {
    int jc = j0 + ch * 64;
#pragma unroll
    for (int f = 0; f < 8; ++f) {
      int lin = f * 256 + t;
      int r = lin >> 4, c4 = lin & 15;
      int sa = r * 72 + c4 * 4;
      int jb = jc + c4 * 4;
      float4 va = {0.f, 0.f, 0.f, 0.f}, vb = {0.f, 0.f, 0.f, 0.f};
      if (jb < jlim) {
        float4 mm = *(const float4*)&m[jb];
        va = *(const float4*)&V[(size_t)(bi * 128 + r) * NN + jb];
        vb = *(const float4*)&V[(size_t)(bj * 128 + r) * NN + jb];
        va.x -= mm.x; va.y -= mm.y; va.z -= mm.z; va.w -= mm.w;
        vb.x -= mm.x; vb.y -= mm.y; vb.z -= mm.z; vb.w -= mm.w;
      }
      cvt_write(va, Ah, Al, sa);
      cvt_write(vb, Bh, Bl, sa);
    }
    __syncthreads();
#pragma unroll
    for (int ks = 0; ks < 2; ++ks) {
      int kb = ks * 32 + lq * 8;
      bf16x8 ah[4], al[4], bh[4], bl[4];
#pragma unroll
      for (int mi = 0; mi < 4; ++mi) {
        int ro = (m0 + mi * 16 + lrow) * 72 + kb;
        ah[mi] = *(const bf16x8*)&Ah[ro];
        al[mi] = *(const bf16x8*)&Al[ro];
      }
#pragma unroll
      for (int nj = 0; nj < 4; ++nj) {
        int ro = (n0 + nj * 16 + lrow) * 72 + kb;
        bh[nj] = *(const bf16x8*)&Bh[ro];
        bl[nj] = *(const bf16x8*)&Bl[ro];
      }
#pragma unroll
      for (int mi = 0; mi < 4; ++mi)
#pragma unroll
        for (int nj = 0; nj < 4; ++nj) {
          acc[mi][nj] = __builtin_amdgcn_mfma_f32_16x16x32_bf16(ah[mi], bh[nj], acc[mi][nj], 0, 0, 0);
          acc[mi][nj] = __builtin_amdgcn_mfma_f32_16x16x32_bf16(ah[mi], bl[nj], acc[mi][nj], 0, 0, 0);
          acc[mi][nj] = __builtin_amdgcn_mfma_f32_16x16x32_bf16(al[mi], bh[nj], acc[mi][nj], 0, 0, 0);
        }
    }
    __syncthreads();
  }
#pragma unroll
  for (int mi = 0; mi < 4; ++mi)
#pragma unroll
    for (int nj = 0; nj < 4; ++nj)
#pragma unroll
      for (int r = 0; r < 4; ++r) {
        int row = bi * 128 + m0 + mi * 16 + lq * 4 + r;
        int col = bj * 128 + n0 + nj * 16 + lrow;
        atomicAdd(&UUT[row * 256 + col], acc[mi][nj][r]);
      }
}

// ---------------- column sums & sumsq of X (atomic) ----------------
__global__ void k_colstatX(const float* __restrict__ X, float* __restrict__ colsum,
                           float* __restrict__ colss) {
  int b = blockIdx.x, t = threadIdx.x;
  int r0 = b * 196;
  int r1 = r0 + 196; if (r1 > NN) r1 = NN;
  float s1 = 0, ss1 = 0, s2 = 0, ss2 = 0;
  for (int r = r0; r < r1; ++r) {
    float v1 = X[(size_t)r * 512 + t], v2 = X[(size_t)r * 512 + t + 256];
    s1 += v1; ss1 += v1 * v1; s2 += v2; ss2 += v2 * v2;
  }
  atomicAdd(&colsum[t], s1);       atomicAdd(&colss[t], ss1);
  atomicAdd(&colsum[t + 256], s2); atomicAdd(&colss[t + 256], ss2);
}

// ---------------- per-row squared norm of X ----------------
__global__ void k_xsq(const float* __restrict__ X, float* __restrict__ xsq) {
  int row = blockIdx.x * 4 + (threadIdx.x >> 6);
  int lane = threadIdx.x & 63;
  const float* Xr = X + (size_t)row * 512;
  float s = 0.f;
#pragma unroll
  for (int d = 0; d < 8; ++d) { float v = Xr[lane + 64 * d]; s += v * v; }
  s = waveSum(s);
  if (lane == 0) xsq[row] = s;
}

// ---------------- column means of T ----------------
__global__ void k_colmeanT(const float* __restrict__ T, float* __restrict__ mu) {
  int c = threadIdx.x;
  float s = 0.f;
  for (int r = 0; r < 256; ++r) s += T[r * 512 + c];
  mu[c] = s * (1.0f / 256.0f);
}

// ---------------- Tc = T - mu, accumulate sum(Tc^2) ----------------
__global__ void k_centerT(const float* __restrict__ T, const float* __restrict__ mu,
                          float* __restrict__ Tc, float* __restrict__ scal) {
  __shared__ float red[4];
  int t = threadIdx.x;
  int base = blockIdx.x * 1024;
  float ss = 0.f;
#pragma unroll
  for (int p = 0; p < 4; ++p) {
    int l = base + p * 256 + t;
    float v = T[l] - mu[l & 511];
    Tc[l] = v;
    ss += v * v;
  }
  ss = waveSum(ss);
  if ((t & 63) == 0) red[t >> 6] = ss;
  __syncthreads();
  if (t == 0) atomicAdd(&scal[0], red[0] + red[1] + red[2] + red[3]);
}

// ---------------- trace of cov(X) ----------------
__global__ void k_trCX(const float* __restrict__ colsum, const float* __restrict__ colss,
                       float* __restrict__ scal) {
  __shared__ float red[8];
  int t = threadIdx.x;  // 512
  float mu = colsum[t] * (1.0f / 50000.0f);
  float v = (colss[t] - 50000.0f * mu * mu) * (1.0f / 49999.0f);
  v = waveSum(v);
  if ((t & 63) == 0) red[t >> 6] = v;
  __syncthreads();
  if (t == 0) {
    float s = 0;
    for (int i = 0; i < 8; ++i) s += red[i];
    scal[1] = s;
  }
}

// ---------------- colmeans of V -> m ----------------
__global__ void k_vstats(const float* __restrict__ V, float* __restrict__ m) {
  int j = blockIdx.x * 256 + threadIdx.x;
  if (j >= NN) return;
  float s = 0.f;
  for (int i = 0; i < 256; ++i) s += V[(size_t)i * NN + j];
  m[j] = s * (1.0f / 256.0f);
}

// ---------------- w_i = Tc_i . muX ----------------
__global__ void __launch_bounds__(256) k_wvec(const float* __restrict__ T,
                                              const float* __restrict__ colsum,
                                              float* __restrict__ w) {
  __shared__ float cs[512];
  __shared__ float red[4];
  int t = threadIdx.x;
  cs[t] = colsum[t] * (1.0f / 50000.0f);
  cs[t + 256] = colsum[t + 256] * (1.0f / 50000.0f);
  __syncthreads();
  float a = 0.f;
  for (int c = 0; c < 512; ++c) a += T[t * 512 + c] * cs[c];
  float s = waveSum(a);
  if ((t & 63) == 0) red[t >> 6] = s;
  __syncthreads();
  float mean = (red[0] + red[1] + red[2] + red[3]) * (1.0f / 256.0f);
  w[t] = a - mean;
}

// ---------------- H = (UUT - N w w^T)/(49999*255) + rhoX * TcTc/255 ----------------
__global__ void k_hfix(const float* __restrict__ UUT, const float* __restrict__ TcTc,
                       const float* __restrict__ w, const float* __restrict__ scal,
                       float* __restrict__ H) {
  int l = blockIdx.x * 256 + threadIdx.x;
  int i = l >> 8, j = l & 255;
  float u = (i >= 128 && j < 128) ? UUT[j * 256 + i] : UUT[i * 256 + j];
  float rho = scal[1] * (1e-3f / 512.0f);
  H[l] = (u - 50000.0f * w[i] * w[j]) * (1.0f / (49999.0f * 255.0f))
       + rho * TcTc[i * 256 + j] * (1.0f / 255.0f);
}

// ---------------- cooperative NS: power + init + 11 iters + trace, one launch ----------------
__global__ void __launch_bounds__(256) k_ns_all(const float* __restrict__ H,
                                                float* __restrict__ scal,
                                                float* __restrict__ Y, float* __restrict__ Z,
                                                float* __restrict__ Y2, float* __restrict__ Z2,
                                                float* __restrict__ Pm) {
  cg::grid_group grid = cg::this_grid();
  __shared__ float As[64][65], Bs[64][65];
  __shared__ float pvec[256], nvv[256], red[8];
  int blk = blockIdx.x, t = threadIdx.x;
  int tr = t >> 4, tc = t & 15;
  float rt = scal[0] * (1.0f / 255.0f) * (1e-3f / 512.0f);

  // power iteration (block 0)
  if (blk == 0) {
    pvec[t] = 1.0f;
    __syncthreads();
    float n2 = 256.0f, n3 = 256.0f;
    for (int it = 0; it < 3; ++it) {
      float s = rt * pvec[t];
      for (int j = 0; j < 256; ++j) s += H[t * 256 + j] * pvec[j];
      nvv[t] = s;
      float ss = waveSum(s * s);
      if ((t & 63) == 0) red[t >> 6] = ss;
      __syncthreads();
      float norm2 = red[0] + red[1] + red[2] + red[3];
      if (it == 1) n2 = norm2;
      if (it == 2) n3 = norm2;
      pvec[t] = nvv[t];
      __syncthreads();
    }
    float d = H[t * 256 + t] + rt;
#pragma unroll
    for (int off = 32; off > 0; off >>= 1) d = fmaxf(d, __shfl_xor(d, off));
    if ((t & 63) == 0) red[t >> 6] = d;
    __syncthreads();
    if (t == 0) {
      float lam = sqrtf(n3 / n2);
      float md = fmaxf(fmaxf(red[0], red[1]), fmaxf(red[2], red[3]));
      scal[5] = fmaxf(1.3f * lam, md);
    }
  }
  grid.sync();
  // init Y0, Z0
  {
    float inv = 1.0f / scal[5];
#pragma unroll
    for (int p = 0; p < 8; ++p) {
      int l = blk * 2048 + p * 256 + t;
      int i = l >> 8, j = l & 255;
      Y[l] = (H[l] + ((i == j) ? rt : 0.f)) * inv;
      Z[l] = (i == j) ? 1.0f : 0.f;
    }
  }
  grid.sync();
  float* y = Y; float* z = Z; float* yn = Y2; float* zn = Z2;
  for (int it = 0; it < NS_ITERS; ++it) {
    if (blk < 16) {
      int bi = blk >> 2, bj = blk & 3;
      float acc[4][4] = {{0.f}};
      for (int k0 = 0; k0 < 256; k0 += 64) {
#pragma unroll
        for (int p = 0; p < 16; ++p) {
          int l = t + 256 * p;
          int r = l >> 6, c = l & 63;
          As[r][c] = z[(bi * 64 + r) * 256 + k0 + c];
          Bs[r][c] = y[(k0 + r) * 256 + bj * 64 + c];
        }
        __syncthreads();
#pragma unroll 16
        for (int kk = 0; kk < 64; ++kk) {
          float a[4], b[4];
#pragma unroll
          for (int u = 0; u < 4; ++u) a[u] = As[tr + 16 * u][kk];
#pragma unroll
          for (int v = 0; v < 4; ++v) b[v] = Bs[kk][tc + 16 * v];
#pragma unroll
          for (int u = 0; u < 4; ++u)
#pragma unroll
            for (int v = 0; v < 4; ++v) acc[u][v] += a[u] * b[v];
        }
        __syncthreads();
      }
#pragma unroll
      for (int u = 0; u < 4; ++u)
#pragma unroll
        for (int v = 0; v < 4; ++v)
          Pm[(bi * 64 + tr + 16 * u) * 256 + bj * 64 + tc + 16 * v] = acc[u][v];
    }
    grid.sync();
    {
      int zz = blk >> 4, bi = (blk >> 2) & 3, bj = blk & 3;
      const float* A = zz ? Pm : y;
      const float* B = zz ? z : Pm;
      const float* D = zz ? z : y;
      float* O = zz ? zn : yn;
      float acc[4][4] = {{0.f}};
      for (int k0 = 0; k0 < 256; k0 += 64) {
#pragma unroll
        for (int p = 0; p < 16; ++p) {
          int l = t + 256 * p;
          int r = l >> 6, c = l & 63;
          As[r][c] = A[(bi * 64 + r) * 256 + k0 + c];
          Bs[r][c] = B[(k0 + r) * 256 + bj * 64 + c];
        }
        __syncthreads();
#pragma unroll 16
        for (int kk = 0; kk < 64; ++kk) {
          float a[4], b[4];
#pragma unroll
          for (int u = 0; u < 4; ++u) a[u] = As[tr + 16 * u][kk];
#pragma unroll
          for (int v = 0; v < 4; ++v) b[v] = Bs[kk][tc + 16 * v];
#pragma unroll
          for (int u = 0; u < 4; ++u)
#pragma unroll
            for (int v = 0; v < 4; ++v) acc[u][v] += a[u] * b[v];
        }
        __syncthreads();
      }
#pragma unroll
      for (int u = 0; u < 4; ++u)
#pragma unroll
        for (int v = 0; v < 4; ++v) {
          int idx = (bi * 64 + tr + 16 * u) * 256 + bj * 64 + tc + 16 * v;
          O[idx] = 1.5f * D[idx] - 0.5f * acc[u][v];
        }
    }
    grid.sync();
    float* tp = y; y = yn; yn = tp;
    tp = z; z = zn; zn = tp;
  }
  // trace
  if (blk == 0) {
    float v = y[t * 256 + t];
    v = waveSum(v);
    if ((t & 63) == 0) red[t >> 6] = v;
    __syncthreads();
    if (t == 0) {
      float trY = red[0] + red[1] + red[2] + red[3];
      scal[2] = sqrtf(scal[5]) * trY + 256.0f * sqrtf(rt);
    }
  }
}

// ---------------- stage 1: threshold-filter exact top-32 per (query, 1/8-slice) ----------------
__global__ void __launch_bounds__(256) k_topk_part(const float* __restrict__ V,
                                                   const float* __restrict__ xsq,
                                                   float* __restrict__ candv,
                                                   int* __restrict__ candi) {
  __shared__ float bufv[512];
  __shared__ int bufi[512];
  __shared__ int lcount;
  __shared__ float tvs;
  __shared__ int tis;
  int part = blockIdx.x, q = blockIdx.y, t = threadIdx.x;
  int base = part * PCH;
  int lane = t & 63;
  if (t == 0) { lcount = 0; tvs = FLT_MAX; tis = 0x7fffffff; }
  __syncthreads();
  const float* rowV = V + (size_t)q * NN + base;
  const float* xs = xsq + base;

  auto flush = [&]() {
    __syncthreads();
    int c = lcount;
    for (int s = c + t; s < 512; s += 256) { bufv[s] = FLT_MAX; bufi[s] = 0x7fffffff; }
    __syncthreads();
    for (int ssz = 2; ssz <= 512; ssz <<= 1) {
      for (int st = ssz >> 1; st > 0; st >>= 1) {
        int i = 2 * t - (t & (st - 1));
        int j = i + st;
        bool up = ((i & ssz) == 0);
        float a = bufv[i], b = bufv[j];
        int ai = bufi[i], bi2 = bufi[j];
        bool agtb = (a > b) || (a == b && ai > bi2);
        if (agtb == up) { bufv[i] = b; bufv[j] = a; bufi[i] = bi2; bufi[j] = ai; }
        __syncthreads();
      }
    }
    if (t == 0) { lcount = 32; tvs = bufv[31]; tis = bufi[31]; }
    __syncthreads();
  };

  int ntile = (PCH + 255) >> 8;
  for (int tile = 0; tile < ntile; ++tile) {
    int j = tile * 256 + t;
    float val = 0.f; int idx = 0;
    bool pred = false;
    if (j < PCH) {
      val = xs[j] - 2.0f * rowV[j];
      idx = base + j;
      float tv = tvs; int ti = tis;
      pred = (val < tv) || (val == tv && idx < ti);
    }
    unsigned long long mask = __ballot(pred);
    if (mask) {
      int lead = __ffsll((unsigned long long)mask) - 1;
      int cnt = __popcll(mask);
      int basep = 0;
      if (lane == lead) basep = atomicAdd(&lcount, cnt);
      basep = __shfl(basep, lead);
      if (pred) {
        int off = __popcll(mask & ((1ull << lane) - 1ull));
        int slot = basep + off;
        bufv[slot] = val; bufi[slot] = idx;
      }
    }
    __syncthreads();
    if (lcount >= 256) flush();
  }
  flush();
  if (t < 32) {
    candv[(q * PARTS + part) * 32 + t] = bufv[t];
    candi[(q * PARTS + part) * 32 + t] = bufi[t];
  }
}

// ---------------- stage 2: bitonic-sort 256 candidates, emit top-32 indices ----------------
__global__ void __launch_bounds__(128) k_topk_final(const float* __restrict__ candv,
                                                    const int* __restrict__ candi,
                                                    int* __restrict__ runi) {
  __shared__ float v[256];
  __shared__ int ix[256];
  int q = blockIdx.x, t = threadIdx.x;
  v[t] = candv[q * 256 + t];
  v[t + 128] = candv[q * 256 + t + 128];
  ix[t] = candi[q * 256 + t];
  ix[t + 128] = candi[q * 256 + t + 128];
  __syncthreads();
  for (int ssz = 2; ssz <= 256; ssz <<= 1) {
    for (int st = ssz >> 1; st > 0; st >>= 1) {
      int i = 2 * t - (t & (st - 1));
      int j = i + st;
      bool up = ((i & ssz) == 0);
      float a = v[i], b = v[j];
      int ai = ix[i], bi = ix[j];
      bool agtb = (a > b) || (a == b && ai > bi);
      if (agtb == up) { v[i] = b; v[j] = a; ix[i] = bi; ix[j] = ai; }
      __syncthreads();
    }
  }
  if (t < 32) runi[q * 32 + t] = ix[t];
}

// ---------------- l2 to neighbors, softmax post_w, normalized pre_w ----------------
__global__ void __launch_bounds__(64) k_l2soft(const float* __restrict__ T, const float* __restrict__ X,
                                               const int* __restrict__ runi, const int* __restrict__ qidx,
                                               const float* __restrict__ prew, float* __restrict__ postw,
                                               float* __restrict__ prewn) {
  __shared__ float l2s[32];
  int b = blockIdx.x, lane = threadIdx.x;
  int qi = qidx[b];
  float pwv = (lane < 32) ? fmaxf(prew[qi * 32 + lane], 1e-8f) : 0.f;
  float psum = waveSum(pwv);
  if (lane < 32) prewn[b * 32 + lane] = pwv / psum;
  const float* Tb = T + b * 512;
  for (int n = 0; n < 32; ++n) {
    int nb = runi[b * 32 + n];
    const float* Xr = X + (size_t)nb * 512;
    float acc = 0.f;
#pragma unroll
    for (int d = 0; d < 8; ++d) {
      float df = Tb[lane + 64 * d] - Xr[lane + 64 * d];
      acc += df * df;
    }
    acc = waveSum(acc);
    if (lane == 0) l2s[n] = acc;
  }
  __syncthreads();
  float lg = (lane < 32) ? (-l2s[lane] * 10.0f) : -FLT_MAX;
  float mx = lg;
#pragma unroll
  for (int off = 32; off > 0; off >>= 1) mx = fmaxf(mx, __shfl_xor(mx, off));
  float e = (lane < 32) ? expf(lg - mx) : 0.f;
  float es = waveSum(e);
  float wv = e / es;
  wv = fmaxf(wv, 1e-8f);
  float ws2 = (lane < 32) ? wv : 0.f;
  ws2 = waveSum(ws2);
  if (lane < 32) postw[b * 32 + lane] = wv / ws2;
}

// ---------------- per-batch pre: Gram -> C -> median -> K; write Kg, Mg=K*Cn ----------------
__global__ void __launch_bounds__(256) k_batch_pre(const float* __restrict__ X, const int* __restrict__ qidx,
                                                   const int* __restrict__ pre_idx, const int* __restrict__ runi,
                                                   float* __restrict__ Kg, float* __restrict__ Mg) {
  __shared__ float G[64][65];
  __shared__ float Cm[64][65];
  __shared__ float SB[4160];
  __shared__ int supp[64];
  __shared__ float medsh;
  int b = blockIdx.x, t = threadIdx.x;
  if (t < 32) supp[t] = pre_idx[qidx[b] * 32 + t];
  else if (t < 64) supp[t] = runi[b * 32 + t - 32];
  __syncthreads();
  int tr = t >> 4, tc = t & 15;
  float acc[4][4] = {{0.f}};
  for (int kc = 0; kc < 512; kc += 64) {
    __syncthreads();
#pragma unroll
    for (int p2 = 0; p2 < 16; ++p2) {
      int l = t + 256 * p2;
      int r = l >> 6, c = l & 63;
      SB[r * 65 + c] = X[(size_t)supp[r] * 512 + kc + c];
    }
    __syncthreads();
#pragma unroll 8
    for (int kk = 0; kk < 64; ++kk) {
      float a[4], bb[4];
#pragma unroll
      for (int u = 0; u < 4; ++u) a[u] = SB[(tr * 4 + u) * 65 + kk];
#pragma unroll
      for (int v = 0; v < 4; ++v) bb[v] = SB[(tc * 4 + v) * 65 + kk];
#pragma unroll
      for (int u = 0; u < 4; ++u)
#pragma unroll
        for (int v = 0; v < 4; ++v) acc[u][v] += a[u] * bb[v];
    }
  }
  __syncthreads();
#pragma unroll
  for (int u = 0; u < 4; ++u)
#pragma unroll
    for (int v = 0; v < 4; ++v) G[tr * 4 + u][tc * 4 + v] = acc[u][v];
  __syncthreads();
  for (int l = t; l < 4096; l += 256) {
    int i = l >> 6, j = l & 63;
    float cc = fmaxf(G[i][i] + G[j][j] - 2.0f * G[i][j], 0.f);
    Cm[i][j] = cc;
    SB[l] = cc;
  }
  for (int ssz = 2; ssz <= 4096; ssz <<= 1) {
    for (int st = ssz >> 1; st > 0; st >>= 1) {
      __syncthreads();
      for (int l = t; l < 2048; l += 256) {
        int i = 2 * l - (l & (st - 1));
        int j = i + st;
        bool up = ((i & ssz) == 0);
        float a = SB[i], b2 = SB[j];
        if ((a > b2) == up) { SB[i] = b2; SB[j] = a; }
      }
    }
  }
  __syncthreads();
  if (t == 0) medsh = 0.5f * (SB[2047] + SB[2048]) + 1e-8f;
  __syncthreads();
  float inv = 1.0f / medsh;
  for (int l = t; l < 4096; l += 256) {
    int i = l >> 6, j = l & 63;
    float cn = Cm[i][j] * inv;
    float kv = expf(-cn * 10.0f);
    Kg[(size_t)b * 4096 + l] = kv;
    Mg[(size_t)b * 4096 + l] = kv * cn;
  }
}

// ---------------- one-wave Sinkhorn per batch element, early exact exit ----------------
__global__ void __launch_bounds__(64) k_sink(const float* __restrict__ Kg,
                                             const float* __restrict__ Mg,
                                             const float* __restrict__ prewn,
                                             const float* __restrict__ postw,
                                             float* __restrict__ scal) {
  __shared__ float ubuf[64], vbuf[64];
  int b = blockIdx.x, lane = threadIdx.x;
  const float* Kb = Kg + (size_t)b * 4096;
  float4 krow[16], ktrow[16];
#pragma unroll
  for (int c = 0; c < 16; ++c)
    krow[c] = *(const float4*)&Kb[lane * 64 + c * 4];
#pragma unroll
  for (int c = 0; c < 16; ++c) {
    ktrow[c].x = Kb[(c * 4 + 0) * 64 + lane];
    ktrow[c].y = Kb[(c * 4 + 1) * 64 + lane];
    ktrow[c].z = Kb[(c * 4 + 2) * 64 + lane];
    ktrow[c].w = Kb[(c * 4 + 3) * 64 + lane];
  }
  float p = (lane < 32) ? prewn[b * 32 + lane] : 0.f;
  float qv = (lane < 32) ? 0.f : postw[b * 32 + (lane - 32)];
  vbuf[lane] = 1.0f;
  __syncthreads();
  float u = 0.f, vcur = 1.0f;
  float pu = -1e30f, pv = -1e30f;
  for (int it = 0; it < 200; ++it) {
    float s = 0.f;
#pragma unroll
    for (int c = 0; c < 16; ++c) {
      float4 v4 = *(const float4*)&vbuf[c * 4];
      s += krow[c].x * v4.x + krow[c].y * v4.y + krow[c].z * v4.z + krow[c].w * v4.w;
    }
    u = p / (s + 1e-16f);
    ubuf[lane] = u;
    __syncthreads();
    float s2 = 0.f;
#pragma unroll
    for (int c = 0; c < 16; ++c) {
      float4 u4 = *(const float4*)&ubuf[c * 4];
      s2 += ktrow[c].x * u4.x + ktrow[c].y * u4.y + ktrow[c].z * u4.z + ktrow[c].w * u4.w;
    }
    vcur = qv / (s2 + 1e-16f);
    vbuf[lane] = vcur;
    __syncthreads();
    if ((it & 7) == 7) {
      unsigned long long ch = __ballot(u != pu || vcur != pv);
      if (ch == 0ull) break;
      pu = u; pv = vcur;
    }
  }
  // loss = sum_i u_i * (M v)_i
  const float* Mb = Mg + (size_t)b * 4096;
  float s3 = 0.f;
#pragma unroll
  for (int c = 0; c < 16; ++c) {
    float4 m4 = *(const float4*)&Mb[lane * 64 + c * 4];
    float4 v4 = *(const float4*)&vbuf[c * 4];
    s3 += m4.x * v4.x + m4.y * v4.y + m4.z * v4.z + m4.w * v4.w;
  }
  float contrib = waveSum(u * s3);
  if (lane == 0) atomicAdd(&scal[3], contrib * (1.0f / 256.0f));
}

// ---------------- sum(W^2) ----------------
__global__ void k_wreg(const float* __restrict__ W, float* __restrict__ scal) {
  __shared__ float red[4];
  int t = threadIdx.x;
  int base = blockIdx.x * 2048;
  float ss = 0.f;
#pragma unroll
  for (int p = 0; p < 8; ++p) {
    float v = W[base + p * 256 + t];
    ss += v * v;
  }
  ss = waveSum(ss);
  if ((t & 63) == 0) red[t >> 6] = ss;
  __syncthreads();
  if (t == 0) atomicAdd(&scal[4], red[0] + red[1] + red[2] + red[3]);
}

// ---------------- final combine ----------------
__global__ void k_combine(const float* __restrict__ mu_t, const float* __restrict__ colsum,
                          const float* __restrict__ scal, float* __restrict__ out) {
  __shared__ float red[8];
  int t = threadIdx.x;  // 512
  float dm = mu_t[t] - colsum[t] * (1.0f / 50000.0f);
  float v = dm * dm;
  v = waveSum(v);
  if ((t & 63) == 0) red[t >> 6] = v;
  __syncthreads();
  if (t == 0) {
    float term_mean = 0.f;
    for (int i = 0; i < 8; ++i) term_mean += red[i];
    float trCT = scal[0] * (1.0f / 255.0f);
    float trCX = scal[1];
    float S = scal[2];
    float term_cov = trCX * 1.001f + trCT * 1.001f - 2.0f * S;
    term_cov = fmaxf(term_cov, 0.f);
    float loss_dist = term_mean + term_cov;
    float loss_knn = scal[3];
    float loss_reg = 0.5f * scal[4];
    out[0] = loss_dist + loss_knn + 1e-4f * loss_reg;
    out[1] = loss_dist;
    out[2] = loss_knn;
  }
}

extern "C" void kernel_launch(void* const* d_in, const int* in_sizes, int n_in,
                              void* d_out, int out_size, void* d_ws, size_t ws_size,
                              hipStream_t stream) {
  const float* q = (const float*)d_in[0];
  const int* qidx = (const int*)d_in[1];
  const float* W = (const float*)d_in[2];
  const float* X = (const float*)d_in[3];
  const int* pre_idx = (const int*)d_in[4];
  const float* prew = (const float*)d_in[5];
  float* out = (float*)d_out;
  float* ws = (float*)d_ws;

  float* scal = ws + OFF_SC;
  float* colsum = ws + OFF_CS;
  float* colss = ws + OFF_CSS;
  float* T = ws + OFF_T;
  float* Tc = ws + OFF_TC;
  float* H = ws + OFF_H;
  float* mu_t = ws + OFF_MUT;
  float* xsq = ws + OFF_XSQ;
  int* runi = (int*)(ws + OFF_RUNI);
  float* postw = ws + OFF_PW;
  float* prewn = ws + OFF_PRW;
  float* V = ws + OFF_D2;
  float* UUT = ws + OFF_UUT;
  float* TcTc = ws + OFF_TCTC;
  float* wv = ws + OFF_W;
  float* m = ws + OFF_M;
  float* candv = ws + OFF_P;
  int* candi = (int*)(ws + OFF_P + 65536);
  float* Kg = ws + OFF_KG;
  float* Mg = ws + OFF_MG;

  hipMemsetAsync(d_ws, 0, (size_t)ZERO_F * 4, stream);

  // T = q @ W
  k_g64_nn<<<dim3(8, 4), 256, 0, stream>>>(q, W, T, 512, 512, 512, 512, 1.0f);
  // X stats
  k_colstatX<<<256, 256, 0, stream>>>(X, colsum, colss);
  k_xsq<<<12500, 256, 0, stream>>>(X, xsq);
  // T stats
  k_colmeanT<<<1, 512, 0, stream>>>(T, mu_t);
  k_centerT<<<128, 256, 0, stream>>>(T, mu_t, Tc, scal);
  k_trCX<<<1, 512, 0, stream>>>(colsum, colss, scal);
  // V = T @ X^T (MFMA)
  k_vgemm<<<dim3(391, 2), 256, 0, stream>>>(T, X, V);
  k_vstats<<<196, 256, 0, stream>>>(V, m);
  // kNN top-32 from d2 = xsq - 2V
  k_topk_part<<<dim3(PARTS, 256), 256, 0, stream>>>(V, xsq, candv, candi);
  k_topk_final<<<256, 128, 0, stream>>>(candv, candi, runi);
  // H assembly
  k_g64_nt<<<dim3(4, 4), 256, 0, stream>>>(Tc, Tc, TcTc, 512, 512, 512, 256, 1.0f);
  k_wvec<<<1, 256, 0, stream>>>(T, colsum, wv);
  k_uut<<<dim3(3, 50), 256, 0, stream>>>(V, m, UUT);
  k_hfix<<<256, 256, 0, stream>>>(UUT, TcTc, wv, scal, H);
  // spectral sum: one cooperative launch (power + init + NS iters + trace)
  {
    float* Y = ws + OFF_TC;
    float* Z = ws + OFF_TC + 65536;
    float* Y2 = ws + OFF_P;
    float* Z2 = ws + OFF_P + 65536;
    float* Pm = ws + OFF_G;
    const float* Hc = H;
    void* args[] = {(void*)&Hc, (void*)&scal, (void*)&Y, (void*)&Z,
                    (void*)&Y2, (void*)&Z2, (void*)&Pm};
    hipLaunchCooperativeKernel((void*)k_ns_all, dim3(32), dim3(256), args, 0, stream);
  }
  // kNN OT loss
  k_l2soft<<<256, 64, 0, stream>>>(T, X, runi, qidx, prew, postw, prewn);
  k_batch_pre<<<256, 256, 0, stream>>>(X, qidx, pre_idx, runi, Kg, Mg);
  k_sink<<<256, 64, 0, stream>>>(Kg, Mg, prewn, postw, scal);
  k_wreg<<<128, 256, 0, stream>>>(W, scal);
  k_combine<<<1, 512, 0, stream>>>(mu_t, colsum, scal, out);
}